// Round 1
// baseline (741.202 us; speedup 1.0000x reference)
//
#include <hip/hip_runtime.h>

#define ALPHA_F 32.0f
#define EPS_F 1e-8f
#define NEG_SLOPE_F 0.01f

#define D_IN 4096
#define D_OUT 4096
#define RNK 16
#define N_ROWS 16384

// =====================================================================
// K0: WaT[r][d] = Wa[d][r]   (256 KiB one-off; write-coalesced)
// =====================================================================
__global__ __launch_bounds__(256) void wa_transpose(
    const float* __restrict__ Wa, float* __restrict__ WaT)
{
    const int idx = blockIdx.x * 256 + threadIdx.x;   // 0..65535
    const int d = idx & (D_IN - 1);
    const int r = idx >> 12;                           // D_IN = 2^12
    WaT[idx] = Wa[d * RNK + r];
}

// =====================================================================
// K1: u[row][r] = ALPHA * (new_x + leaky(minmaxnorm(h@Wc + new_x@Wd + h)))
//
// 4 waves/block, 4 rows/wave: 16-lane group per row.
// Lane (g,q): g = row-in-wave, q = lane's d-phase; sweeps d4 = q + 16k.
//   -> x loads:   4 rows x 256B contiguous per instr (coalesced)
//   -> WaT loads: 16 consecutive float4 per group, dup'd across groups
//                 (same-line requests merge in the coalescer)
// Register-exchange butterfly leaves lane q owning rank r==q, so the
// whole rank-16 stage (h@Wc + nx@Wd + h, min-max, leaky) runs on
// intra-group shuffles with zero LDS.
// =====================================================================
__global__ __launch_bounds__(256, 4) void ssm_stage1(
    const float* __restrict__ x,
    const float* __restrict__ h_t,
    const float* __restrict__ WaT,
    const float* __restrict__ Wc,
    const float* __restrict__ Wd,
    float* __restrict__ u)
{
    const int tid  = threadIdx.x;
    const int lane = tid & 63;
    const int w    = tid >> 6;
    const int g    = lane >> 4;
    const int q    = lane & 15;
    const long row = (long)blockIdx.x * 16 + w * 4 + g;

    const float4* x4  = (const float4*)x + row * (D_IN / 4);
    const float4* wt4 = (const float4*)WaT;

    float acc[RNK];
    #pragma unroll
    for (int r = 0; r < RNK; ++r) acc[r] = 0.0f;

    #pragma unroll 2
    for (int k = 0; k < 64; ++k) {
        const int p = q + (k << 4);
        const float4 xv = x4[p];
        #pragma unroll
        for (int r = 0; r < RNK; ++r) {
            const float4 wv = wt4[r * (D_IN / 4) + p];
            acc[r] += xv.x * wv.x + xv.y * wv.y + xv.z * wv.z + xv.w * wv.w;
        }
    }

    // Exchange-reduce within each 16-lane group. After stage s, each lane
    // holds 8>>s partials; final acc[0] = full d-sum for rank r == q.
    #pragma unroll
    for (int s = 0; s < 4; ++s) {
        const int m = 1 << s;
        const bool up = (lane & m) != 0;
        #pragma unroll
        for (int i = 0; i < (8 >> s); ++i) {
            const float a0 = acc[2 * i], a1 = acc[2 * i + 1];
            const float mine = up ? a1 : a0;
            const float send = up ? a0 : a1;
            acc[i] = mine + __shfl_xor(send, m, 64);
        }
    }
    const float nx = acc[0];   // new_x[row][q]

    // rank-16 stage: h1 = (h @ (Wc + I))[q] + (nx @ Wd)[q]
    const float h_own = h_t[row * RNK + q];
    float h1 = 0.0f;
    #pragma unroll
    for (int j = 0; j < RNK; ++j) {
        const float hj  = __shfl(h_own, j, 16);
        const float nxj = __shfl(nx, j, 16);
        const float wc  = Wc[j * RNK + q] + ((j == q) ? 1.0f : 0.0f);
        h1 += hj * wc + nxj * Wd[j * RNK + q];
    }

    // min/max over the 16 ranks (xor masks < 16 stay in-group)
    float mn = h1, mx = h1;
    #pragma unroll
    for (int m = 1; m <= 8; m <<= 1) {
        mn = fminf(mn, __shfl_xor(mn, m, 64));
        mx = fmaxf(mx, __shfl_xor(mx, m, 64));
    }
    const float hn = (h1 - mn) / (mx - mn + EPS_F);
    const float a  = (hn >= 0.0f) ? hn : NEG_SLOPE_F * hn;
    u[row * RNK + q] = ALPHA_F * (nx + a);
}

// =====================================================================
// K2: y = u @ Wb   (write-bound; Wb loads and y stores fully coalesced)
// 4 waves/block, 4 rows/wave, lanes sweep D_OUT columns.
// =====================================================================
__global__ __launch_bounds__(256) void ssm_stage2(
    const float* __restrict__ u,
    const float* __restrict__ Wb,
    float* __restrict__ y)
{
    const int tid  = threadIdx.x;
    const int lane = tid & 63;
    const int w    = tid >> 6;
    const long row0 = (long)blockIdx.x * 16 + w * 4;

    float4 uu[4][4];
    #pragma unroll
    for (int rr = 0; rr < 4; ++rr) {
        const float4* ur = (const float4*)(u + (row0 + rr) * RNK);
        #pragma unroll
        for (int j = 0; j < 4; ++j) uu[rr][j] = ur[j];
    }

    const float4* Wb4 = (const float4*)Wb;    // [16][1024] float4
    float4* y4 = (float4*)y;
    const long ybase = row0 * (D_OUT / 4);

    for (int k = 0; k < 16; ++k) {
        const int p = lane + (k << 6);
        float4 wb[16];
        #pragma unroll
        for (int r2 = 0; r2 < 16; ++r2) wb[r2] = Wb4[(size_t)r2 * 1024 + p];
        #pragma unroll
        for (int rr = 0; rr < 4; ++rr) {
            float4 o; o.x = 0.0f; o.y = 0.0f; o.z = 0.0f; o.w = 0.0f;
            #pragma unroll
            for (int r2 = 0; r2 < 16; ++r2) {
                const float us = ((const float*)&uu[rr][0])[r2];
                o.x += us * wb[r2].x;
                o.y += us * wb[r2].y;
                o.z += us * wb[r2].z;
                o.w += us * wb[r2].w;
            }
            y4[ybase + (long)rr * (D_OUT / 4) + p] = o;
        }
    }
}

// =====================================================================
// Fallback: previous fused kernel (used only if workspace is too small)
// =====================================================================
__global__ __launch_bounds__(256) void ssm_lora_fused(
    const float* __restrict__ x,
    const float* __restrict__ h_t,
    const float* __restrict__ Wa,
    const float* __restrict__ Wb,
    const float* __restrict__ Wc,
    const float* __restrict__ Wd,
    float* __restrict__ y)
{
    __shared__ float red[4][16][68];
    __shared__ float lds_nx[16][16];
    __shared__ float lds_u[16][16];

    const int tid  = threadIdx.x;
    const int lane = tid & 63;
    const int w    = tid >> 6;
    const long row0 = (long)blockIdx.x * 16;
    const int wr0  = w * 4;

    float acc[4][16];
    #pragma unroll
    for (int rr = 0; rr < 4; ++rr)
        #pragma unroll
        for (int r = 0; r < 16; ++r) acc[rr][r] = 0.0f;

    const float4* x4 = (const float4*)x;
    const long xbase = (row0 + wr0) * (D_IN / 4);

    for (int k = 0; k < 16; ++k) {
        const int p = lane + (k << 6);
        float4 xv[4];
        #pragma unroll
        for (int rr = 0; rr < 4; ++rr)
            xv[rr] = x4[xbase + (long)rr * (D_IN / 4) + p];

        #pragma unroll
        for (int dd = 0; dd < 4; ++dd) {
            const float4* war = (const float4*)(Wa + ((size_t)(4 * p + dd) << 4));
            const float4 w0 = war[0], w1 = war[1], w2 = war[2], w3 = war[3];
            #pragma unroll
            for (int rr = 0; rr < 4; ++rr) {
                const float xs = ((const float*)&xv[rr])[dd];
                acc[rr][0]  += xs * w0.x;  acc[rr][1]  += xs * w0.y;
                acc[rr][2]  += xs * w0.z;  acc[rr][3]  += xs * w0.w;
                acc[rr][4]  += xs * w1.x;  acc[rr][5]  += xs * w1.y;
                acc[rr][6]  += xs * w1.z;  acc[rr][7]  += xs * w1.w;
                acc[rr][8]  += xs * w2.x;  acc[rr][9]  += xs * w2.y;
                acc[rr][10] += xs * w2.z;  acc[rr][11] += xs * w2.w;
                acc[rr][12] += xs * w3.x;  acc[rr][13] += xs * w3.y;
                acc[rr][14] += xs * w3.z;  acc[rr][15] += xs * w3.w;
            }
        }
    }

    #pragma unroll
    for (int rr = 0; rr < 4; ++rr)
        #pragma unroll
        for (int r = 0; r < 16; ++r) {
            float v = acc[rr][r];
            v += __shfl_xor(v, 1, 64);
            v += __shfl_xor(v, 2, 64);
            acc[rr][r] = v;
        }
    if ((lane & 3) == 0) {
        const int li = lane >> 2;
        #pragma unroll
        for (int rr = 0; rr < 4; ++rr)
            #pragma unroll
            for (int r = 0; r < 16; ++r)
                red[w][li][rr * 16 + r] = acc[rr][r];
    }
    __syncthreads();

    {
        const int row  = tid >> 4;
        const int r    = tid & 15;
        const int w2   = tid >> 6;
        const int slot = tid & 63;
        float s = 0.0f;
        #pragma unroll
        for (int i = 0; i < 16; ++i) s += red[w2][i][slot];
        lds_nx[row][r] = s;
        __syncthreads();

        const float* hrow = h_t + (row0 + row) * RNK;
        float h1 = hrow[r];
        #pragma unroll
        for (int j = 0; j < 16; ++j)
            h1 += hrow[j] * Wc[j * 16 + r] + lds_nx[row][j] * Wd[j * 16 + r];

        float mn = h1, mx = h1;
        #pragma unroll
        for (int m = 1; m <= 8; m <<= 1) {
            mn = fminf(mn, __shfl_xor(mn, m, 64));
            mx = fmaxf(mx, __shfl_xor(mx, m, 64));
        }
        const float hn = (h1 - mn) / (mx - mn + EPS_F);
        const float a  = (hn >= 0.0f) ? hn : NEG_SLOPE_F * hn;
        lds_u[row][r] = ALPHA_F * (s + a);
    }
    __syncthreads();

    float4 uu[4][4];
    #pragma unroll
    for (int rr = 0; rr < 4; ++rr)
        #pragma unroll
        for (int j = 0; j < 4; ++j)
            uu[rr][j] = ((const float4*)lds_u[wr0 + rr])[j];

    const float4* Wb4 = (const float4*)Wb;
    float4* y4 = (float4*)y;
    const long ybase = (row0 + wr0) * (D_OUT / 4);

    for (int k = 0; k < 16; ++k) {
        const int p = lane + (k << 6);
        float4 wb[16];
        #pragma unroll
        for (int r2 = 0; r2 < 16; ++r2) wb[r2] = Wb4[(size_t)r2 * 1024 + p];
        #pragma unroll
        for (int rr = 0; rr < 4; ++rr) {
            float4 o; o.x = 0.0f; o.y = 0.0f; o.z = 0.0f; o.w = 0.0f;
            #pragma unroll
            for (int r2 = 0; r2 < 16; ++r2) {
                const float us = ((const float*)&uu[rr][0])[r2];
                o.x += us * wb[r2].x;
                o.y += us * wb[r2].y;
                o.z += us * wb[r2].z;
                o.w += us * wb[r2].w;
            }
            y4[ybase + (long)rr * (D_OUT / 4) + p] = o;
        }
    }
}

extern "C" void kernel_launch(void* const* d_in, const int* in_sizes, int n_in,
                              void* d_out, int out_size, void* d_ws, size_t ws_size,
                              hipStream_t stream) {
    const float* x   = (const float*)d_in[0];
    const float* h_t = (const float*)d_in[1];
    const float* Wa  = (const float*)d_in[2];
    const float* Wb  = (const float*)d_in[3];
    const float* Wc  = (const float*)d_in[4];
    const float* Wd  = (const float*)d_in[5];
    float* y = (float*)d_out;

    const size_t need = (size_t)(RNK * D_IN + (size_t)N_ROWS * RNK) * sizeof(float);
    if (d_ws != nullptr && ws_size >= need) {
        float* WaT = (float*)d_ws;                 // [16][4096]
        float* u   = WaT + (size_t)RNK * D_IN;     // [16384][16]
        wa_transpose<<<dim3((RNK * D_IN) / 256), dim3(256), 0, stream>>>(Wa, WaT);
        ssm_stage1<<<dim3(N_ROWS / 16), dim3(256), 0, stream>>>(x, h_t, WaT, Wc, Wd, u);
        ssm_stage2<<<dim3(N_ROWS / 16), dim3(256), 0, stream>>>(u, Wb, y);
    } else {
        ssm_lora_fused<<<dim3(N_ROWS / 16), dim3(256), 0, stream>>>(x, h_t, Wa, Wb, Wc, Wd, y);
    }
}

// Round 2
// 638.512 us; speedup vs baseline: 1.1608x; 1.1608x over previous
//
#include <hip/hip_runtime.h>

#define ALPHA_F 32.0f
#define EPS_F 1e-8f
#define NEG_SLOPE_F 0.01f

#define D_IN 4096
#define D_OUT 4096
#define RNK 16
#define N_ROWS 16384
#define ROWS_PER_BLOCK 16
#define THREADS 256

// =====================================================================
// K0: WaT[r][d] = Wa[d][r]   (256 KiB one-off; write-coalesced)
// =====================================================================
__global__ __launch_bounds__(256) void wa_transpose(
    const float* __restrict__ Wa, float* __restrict__ WaT)
{
    const int idx = blockIdx.x * 256 + threadIdx.x;   // 0..65535
    const int d = idx & (D_IN - 1);
    const int r = idx >> 12;                           // D_IN = 2^12
    WaT[idx] = Wa[d * RNK + r];
}

// =====================================================================
// Fused kernel v2: round-0 verified structure, phase A rebuilt on WaT.
//   Phase A: acc[4][16] per lane, lane sweeps p = lane + 64k
//            -> x loads 1KB/instr coalesced, WaT loads 1KB/instr coalesced,
//               each WaT load amortized over 4 rows. Rank-halves of 8 keep
//               the wv buffer at 32 VGPR; xn prefetch keeps the x HBM
//               stream deep in flight.
//   Reduce / stage 2 / phase B: byte-identical to the verified round-0.
// =====================================================================
__global__ __launch_bounds__(THREADS) void ssm_lora_fused_v2(
    const float* __restrict__ x,
    const float* __restrict__ h_t,
    const float* __restrict__ WaT,
    const float* __restrict__ Wb,
    const float* __restrict__ Wc,
    const float* __restrict__ Wd,
    float* __restrict__ y)
{
    // stride 68 floats (272B): 16 writers at 272B stride -> 2-way bank alias (free)
    __shared__ float red[4][16][68];
    __shared__ float lds_nx[16][16];
    __shared__ float lds_u[16][16];

    const int tid  = threadIdx.x;
    const int lane = tid & 63;
    const int w    = tid >> 6;
    const long row0 = (long)blockIdx.x * ROWS_PER_BLOCK;
    const int wr0  = w * 4;  // wave's first local row

    // ---------------- Phase A ----------------
    float acc[4][16];
    #pragma unroll
    for (int rr = 0; rr < 4; ++rr)
        #pragma unroll
        for (int r = 0; r < 16; ++r) acc[rr][r] = 0.0f;

    const float4* x4  = (const float4*)x;
    const float4* wt4 = (const float4*)WaT;   // [16][1024] float4
    const long xbase = (row0 + wr0) * (D_IN / 4);

    float4 xv[4];
    #pragma unroll
    for (int rr = 0; rr < 4; ++rr)
        xv[rr] = x4[xbase + (long)rr * (D_IN / 4) + lane];

    for (int k = 0; k < 16; ++k) {
        const int p = lane + (k << 6);   // float4 column index, 0..1023
        float4 xn[4];
        if (k < 15) {
            #pragma unroll
            for (int rr = 0; rr < 4; ++rr)
                xn[rr] = x4[xbase + (long)rr * (D_IN / 4) + p + 64];
        }

        #pragma unroll
        for (int rh = 0; rh < 2; ++rh) {
            float4 wv[8];
            #pragma unroll
            for (int r8 = 0; r8 < 8; ++r8)
                wv[r8] = wt4[(size_t)(rh * 8 + r8) * (D_IN / 4) + p];
            #pragma unroll
            for (int r8 = 0; r8 < 8; ++r8) {
                const int r = rh * 8 + r8;
                #pragma unroll
                for (int rr = 0; rr < 4; ++rr)
                    acc[rr][r] += xv[rr].x * wv[r8].x + xv[rr].y * wv[r8].y
                                + xv[rr].z * wv[r8].z + xv[rr].w * wv[r8].w;
            }
        }

        if (k < 15) {
            #pragma unroll
            for (int rr = 0; rr < 4; ++rr) xv[rr] = xn[rr];
        }
    }

    // partial cross-lane reduce: lanes {4i..4i+3} -> lane 4i holds 4-lane sum
    #pragma unroll
    for (int rr = 0; rr < 4; ++rr)
        #pragma unroll
        for (int r = 0; r < 16; ++r) {
            float v = acc[rr][r];
            v += __shfl_xor(v, 1, 64);
            v += __shfl_xor(v, 2, 64);
            acc[rr][r] = v;
        }
    if ((lane & 3) == 0) {
        const int li = lane >> 2;  // 0..15 partial index
        #pragma unroll
        for (int rr = 0; rr < 4; ++rr)
            #pragma unroll
            for (int r = 0; r < 16; ++r)
                red[w][li][rr * 16 + r] = acc[rr][r];
    }
    __syncthreads();

    // ---------------- Stage 2 (thread t = (row = t>>4, r = t&15)) ----------
    {
        const int row  = tid >> 4;
        const int r    = tid & 15;
        const int w2   = tid >> 6;
        const int slot = tid & 63;
        float s = 0.0f;
        #pragma unroll
        for (int i = 0; i < 16; ++i) s += red[w2][i][slot];
        lds_nx[row][r] = s;
        __syncthreads();

        const float* hrow = h_t + (row0 + row) * RNK;
        float h1 = hrow[r];  // the "+ h_t" term
        #pragma unroll
        for (int j = 0; j < 16; ++j)
            h1 += hrow[j] * Wc[j * 16 + r] + lds_nx[row][j] * Wd[j * 16 + r];

        // min/max over the 16 threads of this row (xor masks < 16 stay in-group)
        float mn = h1, mx = h1;
        #pragma unroll
        for (int m = 1; m <= 8; m <<= 1) {
            mn = fminf(mn, __shfl_xor(mn, m, 64));
            mx = fmaxf(mx, __shfl_xor(mx, m, 64));
        }
        const float hn = (h1 - mn) / (mx - mn + EPS_F);
        const float a  = (hn >= 0.0f) ? hn : NEG_SLOPE_F * hn;
        lds_u[row][r] = ALPHA_F * (s + a);   // fold ALPHA here
    }
    __syncthreads();

    // ---------------- Phase B ----------------
    float4 uu[4][4];
    #pragma unroll
    for (int rr = 0; rr < 4; ++rr)
        #pragma unroll
        for (int j = 0; j < 4; ++j)
            uu[rr][j] = ((const float4*)lds_u[wr0 + rr])[j];

    const float4* Wb4 = (const float4*)Wb;    // [16][1024] float4
    float4* y4 = (float4*)y;
    const long ybase = (row0 + wr0) * (D_OUT / 4);

    for (int k = 0; k < 16; ++k) {
        const int p = lane + (k << 6);
        float4 wb[16];
        #pragma unroll
        for (int r2 = 0; r2 < 16; ++r2) wb[r2] = Wb4[(size_t)r2 * 1024 + p];
        #pragma unroll
        for (int rr = 0; rr < 4; ++rr) {
            float4 o; o.x = 0.0f; o.y = 0.0f; o.z = 0.0f; o.w = 0.0f;
            #pragma unroll
            for (int r2 = 0; r2 < 16; ++r2) {
                const float us = ((const float*)&uu[rr][0])[r2];
                o.x += us * wb[r2].x;
                o.y += us * wb[r2].y;
                o.z += us * wb[r2].z;
                o.w += us * wb[r2].w;
            }
            y4[ybase + (long)rr * (D_OUT / 4) + p] = o;
        }
    }
}

// =====================================================================
// Fallback: round-0 fused kernel (used only if workspace is too small)
// =====================================================================
__global__ __launch_bounds__(THREADS) void ssm_lora_fused(
    const float* __restrict__ x,
    const float* __restrict__ h_t,
    const float* __restrict__ Wa,
    const float* __restrict__ Wb,
    const float* __restrict__ Wc,
    const float* __restrict__ Wd,
    float* __restrict__ y)
{
    __shared__ float red[4][16][68];
    __shared__ float lds_nx[16][16];
    __shared__ float lds_u[16][16];

    const int tid  = threadIdx.x;
    const int lane = tid & 63;
    const int w    = tid >> 6;
    const long row0 = (long)blockIdx.x * ROWS_PER_BLOCK;
    const int wr0  = w * 4;

    float acc[4][16];
    #pragma unroll
    for (int rr = 0; rr < 4; ++rr)
        #pragma unroll
        for (int r = 0; r < 16; ++r) acc[rr][r] = 0.0f;

    const float4* x4 = (const float4*)x;
    const long xbase = (row0 + wr0) * (D_IN / 4);

    for (int k = 0; k < 16; ++k) {
        const int p = lane + (k << 6);
        float4 xv[4];
        #pragma unroll
        for (int rr = 0; rr < 4; ++rr)
            xv[rr] = x4[xbase + (long)rr * (D_IN / 4) + p];

        #pragma unroll
        for (int dd = 0; dd < 4; ++dd) {
            const float4* war = (const float4*)(Wa + ((size_t)(4 * p + dd) << 4));
            const float4 w0 = war[0], w1 = war[1], w2 = war[2], w3 = war[3];
            #pragma unroll
            for (int rr = 0; rr < 4; ++rr) {
                const float xs = ((const float*)&xv[rr])[dd];
                acc[rr][0]  += xs * w0.x;  acc[rr][1]  += xs * w0.y;
                acc[rr][2]  += xs * w0.z;  acc[rr][3]  += xs * w0.w;
                acc[rr][4]  += xs * w1.x;  acc[rr][5]  += xs * w1.y;
                acc[rr][6]  += xs * w1.z;  acc[rr][7]  += xs * w1.w;
                acc[rr][8]  += xs * w2.x;  acc[rr][9]  += xs * w2.y;
                acc[rr][10] += xs * w2.z;  acc[rr][11] += xs * w2.w;
                acc[rr][12] += xs * w3.x;  acc[rr][13] += xs * w3.y;
                acc[rr][14] += xs * w3.z;  acc[rr][15] += xs * w3.w;
            }
        }
    }

    #pragma unroll
    for (int rr = 0; rr < 4; ++rr)
        #pragma unroll
        for (int r = 0; r < 16; ++r) {
            float v = acc[rr][r];
            v += __shfl_xor(v, 1, 64);
            v += __shfl_xor(v, 2, 64);
            acc[rr][r] = v;
        }
    if ((lane & 3) == 0) {
        const int li = lane >> 2;
        #pragma unroll
        for (int rr = 0; rr < 4; ++rr)
            #pragma unroll
            for (int r = 0; r < 16; ++r)
                red[w][li][rr * 16 + r] = acc[rr][r];
    }
    __syncthreads();

    {
        const int row  = tid >> 4;
        const int r    = tid & 15;
        const int w2   = tid >> 6;
        const int slot = tid & 63;
        float s = 0.0f;
        #pragma unroll
        for (int i = 0; i < 16; ++i) s += red[w2][i][slot];
        lds_nx[row][r] = s;
        __syncthreads();

        const float* hrow = h_t + (row0 + row) * RNK;
        float h1 = hrow[r];
        #pragma unroll
        for (int j = 0; j < 16; ++j)
            h1 += hrow[j] * Wc[j * 16 + r] + lds_nx[row][j] * Wd[j * 16 + r];

        float mn = h1, mx = h1;
        #pragma unroll
        for (int m = 1; m <= 8; m <<= 1) {
            mn = fminf(mn, __shfl_xor(mn, m, 64));
            mx = fmaxf(mx, __shfl_xor(mx, m, 64));
        }
        const float hn = (h1 - mn) / (mx - mn + EPS_F);
        const float a  = (hn >= 0.0f) ? hn : NEG_SLOPE_F * hn;
        lds_u[row][r] = ALPHA_F * (s + a);
    }
    __syncthreads();

    float4 uu[4][4];
    #pragma unroll
    for (int rr = 0; rr < 4; ++rr)
        #pragma unroll
        for (int j = 0; j < 4; ++j)
            uu[rr][j] = ((const float4*)lds_u[wr0 + rr])[j];

    const float4* Wb4 = (const float4*)Wb;
    float4* y4 = (float4*)y;
    const long ybase = (row0 + wr0) * (D_OUT / 4);

    for (int k = 0; k < 16; ++k) {
        const int p = lane + (k << 6);
        float4 wb[16];
        #pragma unroll
        for (int r2 = 0; r2 < 16; ++r2) wb[r2] = Wb4[(size_t)r2 * 1024 + p];
        #pragma unroll
        for (int rr = 0; rr < 4; ++rr) {
            float4 o; o.x = 0.0f; o.y = 0.0f; o.z = 0.0f; o.w = 0.0f;
            #pragma unroll
            for (int r2 = 0; r2 < 16; ++r2) {
                const float us = ((const float*)&uu[rr][0])[r2];
                o.x += us * wb[r2].x;
                o.y += us * wb[r2].y;
                o.z += us * wb[r2].z;
                o.w += us * wb[r2].w;
            }
            y4[ybase + (long)rr * (D_OUT / 4) + p] = o;
        }
    }
}

extern "C" void kernel_launch(void* const* d_in, const int* in_sizes, int n_in,
                              void* d_out, int out_size, void* d_ws, size_t ws_size,
                              hipStream_t stream) {
    const float* x   = (const float*)d_in[0];
    const float* h_t = (const float*)d_in[1];
    const float* Wa  = (const float*)d_in[2];
    const float* Wb  = (const float*)d_in[3];
    const float* Wc  = (const float*)d_in[4];
    const float* Wd  = (const float*)d_in[5];
    float* y = (float*)d_out;

    const size_t need = (size_t)RNK * D_IN * sizeof(float);   // 256 KiB
    dim3 grid(N_ROWS / ROWS_PER_BLOCK);
    dim3 block(THREADS);
    if (d_ws != nullptr && ws_size >= need) {
        float* WaT = (float*)d_ws;                 // [16][4096]
        wa_transpose<<<dim3((RNK * D_IN) / 256), dim3(256), 0, stream>>>(Wa, WaT);
        ssm_lora_fused_v2<<<grid, block, 0, stream>>>(x, h_t, WaT, Wb, Wc, Wd, y);
    } else {
        ssm_lora_fused<<<grid, block, 0, stream>>>(x, h_t, Wa, Wb, Wc, Wd, y);
    }
}